// Round 8
// baseline (357.814 us; speedup 1.0000x reference)
//
#include <hip/hip_runtime.h>
#include <hip/hip_bf16.h>
#include <hip/hip_cooperative_groups.h>
#include <math.h>

namespace cg = cooperative_groups;

#define NROWS 8192
#define DDIM  128
#define JCHUNKS 16
#define JPER  (NROWS / JCHUNKS)        // 512 cols per chunk
#define STAGE_COLS 64
#define NSTAGES (JPER / STAGE_COLS)    // 8
#define LOG2E 1.44269504088896f

// fused (cooperative) config: 256 blocks x 1024 thr = 16 waves x 32 rows = 512 rows/block
#define F_ROWS_PER_BLOCK 512
#define F_GRIDX (NROWS / F_ROWS_PER_BLOCK)   // 16
#define F_NBLK  (F_GRIDX * JCHUNKS)          // 256 blocks -> 1/CU, huge residency margin

// fallback (R5, measured 98.7us) config: 512 blocks x 512 thr
#define ROWS_PER_BLOCK 256
#define GRIDX (NROWS / ROWS_PER_BLOCK)       // 32

#define AS1 __attribute__((address_space(1)))
#define AS3 __attribute__((address_space(3)))

typedef __attribute__((ext_vector_type(8))) short bf16x8;  // 8 bf16 = 4 VGPRs
typedef __attribute__((ext_vector_type(4))) float f32x4;

// ======================= shared stats phase body (per-wave, 32 rows) =======================
// Identical math/order to R5: per-row j-sweep = (stage s, ct, p15), 16-lane xor tree.
__device__ __forceinline__ void stats_wave_body(
    const __hip_bfloat16* __restrict__ f1b,
    const float* __restrict__ targets,
    float* __restrict__ partials,
    const char* lds0, const char* lds1, const float* tsh,
    int chunk, int rbase, int lane) {
  const int p15 = lane & 15;
  const int rl4 = lane >> 4;

  bf16x8 afrag[2][4];
  #pragma unroll
  for (int rs = 0; rs < 2; ++rs) {
    const __hip_bfloat16* arow =
        &f1b[(size_t)(rbase + rs * 16 + p15) * DDIM + rl4 * 8];
    #pragma unroll
    for (int ks = 0; ks < 4; ++ks)
      afrag[rs][ks] = *(const bf16x8*)(arow + ks * 32);
  }

  f32x4 ki[2];
  #pragma unroll
  for (int rs = 0; rs < 2; ++rs)
    #pragma unroll
    for (int rr = 0; rr < 4; ++rr)
      ki[rs][rr] = targets[rbase + rs * 16 + rl4 * 4 + rr];

  f32x4 Z[2], Zp[2], Cp[2], Np[2];
  #pragma unroll
  for (int rs = 0; rs < 2; ++rs) {
    Z[rs] = (f32x4){0.f, 0.f, 0.f, 0.f};
    Zp[rs] = (f32x4){0.f, 0.f, 0.f, 0.f};
    Cp[rs] = (f32x4){0.f, 0.f, 0.f, 0.f};
    Np[rs] = (f32x4){0.f, 0.f, 0.f, 0.f};
  }

  for (int s = 0; s < NSTAGES; ++s) {
    // caller synchronizes stages; we just compute on buf (s&1)
    const char* lb = (s & 1) ? lds1 : lds0;
    #pragma unroll
    for (int ct = 0; ct < 4; ++ct) {
      const int rloc = ct * 16 + p15;
      bf16x8 bfrag[4];
      #pragma unroll
      for (int ks = 0; ks < 4; ++ks)
        bfrag[ks] = *(const bf16x8*)(lb + rloc * 256 + (((rl4 + ks * 4) ^ p15) << 4));

      float tj = tsh[s * STAGE_COLS + ct * 16 + p15];
      const bool pj = tj > 0.0f;
      const f32x4 tj4 = {tj, tj, tj, tj};
      const f32x4 K4  = {LOG2E, LOG2E, LOG2E, LOG2E};

      #pragma unroll
      for (int rs = 0; rs < 2; ++rs) {
        f32x4 acc = {0.f, 0.f, 0.f, 0.f};
        #pragma unroll
        for (int ks = 0; ks < 4; ++ks)
          acc = __builtin_amdgcn_mfma_f32_16x16x32_bf16(afrag[rs][ks], bfrag[ks], acc, 0, 0, 0);

        f32x4 c4 = acc;
        f32x4 d4 = ki[rs] - tj4;
        f32x4 m4;
        #pragma unroll
        for (int rr = 0; rr < 4; ++rr) {
          bool q = (__builtin_fabsf(d4[rr]) <= 0.1f) & ((ki[rs][rr] > 0.0f) == pj);
          m4[rr] = q ? 1.0f : 0.0f;
        }
        f32x4 x4 = c4 * K4 - K4;
        f32x4 e4;
        #pragma unroll
        for (int rr = 0; rr < 4; ++rr) e4[rr] = __builtin_amdgcn_exp2f(x4[rr]);
        Z[rs]  += e4;
        Zp[rs] += m4 * e4;
        Cp[rs] += m4 * c4;
        Np[rs] += m4;
      }
    }
    if (s + 1 < NSTAGES) __syncthreads();  // wait next stage's DMA (issued by caller pattern)
  }

  #pragma unroll
  for (int rs = 0; rs < 2; ++rs)
    #pragma unroll
    for (int rr = 0; rr < 4; ++rr)
      #pragma unroll
      for (int off = 1; off < 16; off <<= 1) {
        Z[rs][rr]  += __shfl_xor(Z[rs][rr],  off, 64);
        Zp[rs][rr] += __shfl_xor(Zp[rs][rr], off, 64);
        Cp[rs][rr] += __shfl_xor(Cp[rs][rr], off, 64);
        Np[rs][rr] += __shfl_xor(Np[rs][rr], off, 64);
      }
  if (p15 == 0) {
    #pragma unroll
    for (int rs = 0; rs < 2; ++rs)
      #pragma unroll
      for (int rr = 0; rr < 4; ++rr) {
        size_t row = rbase + rs * 16 + rl4 * 4 + rr;
        f32x4 st = {Z[rs][rr], Zp[rs][rr], Cp[rs][rr], Np[rs][rr]};
        *(f32x4*)&partials[((size_t)row * JCHUNKS + chunk) * 4] = st;
      }
  }
}

// ======================= fused cooperative kernel (256 x 1024) =======================
__global__ __launch_bounds__(1024, 4) void fused_kernel(
    const float* __restrict__ f1, const float* __restrict__ f2,
    const float* __restrict__ targets, float* __restrict__ out,
    __hip_bfloat16* __restrict__ f1b, __hip_bfloat16* __restrict__ f2b,
    float* __restrict__ partials) {
  __shared__ __align__(16) char lds0[STAGE_COLS * 256];   // 16 KB
  __shared__ __align__(16) char lds1[STAGE_COLS * 256];   // 16 KB
  __shared__ __align__(16) float tsh[JPER];               // 2 KB
  __shared__ float wsum[4];

  const int bid = blockIdx.x;
  const int t   = threadIdx.x;
  const int w    = t >> 6;            // 0..15
  const int lane = t & 63;
  const int p15  = lane & 15;
  const int rl4  = lane >> 4;

  // ---------------- phase 1: L2 row-normalize -> bf16 (64 rows/block of 16384) ----------------
  if (bid == 0 && t == 0) out[0] = 0.0f;
  {
    const int rloc = t >> 5;          // 0..31
    const int l    = t & 31;
    #pragma unroll
    for (int pass = 0; pass < 2; ++pass) {
      int gr   = bid * 64 + pass * 32 + rloc;   // 0..16383, each once
      int half = (gr >= NROWS) ? 1 : 0;
      int row  = gr - half * NROWS;
      const float* src = half ? f2 : f1;
      __hip_bfloat16* dst = half ? f2b : f1b;

      float4 v = ((const float4*)src)[row * (DDIM / 4) + l];
      float s = v.x * v.x + v.y * v.y + v.z * v.z + v.w * v.w;
      #pragma unroll
      for (int off = 1; off < 32; off <<= 1) s += __shfl_xor(s, off, 64);
      float inv = 1.0f / fmaxf(sqrtf(s), 1e-12f);
      __hip_bfloat16 hv[4];
      hv[0] = __float2bfloat16(v.x * inv);
      hv[1] = __float2bfloat16(v.y * inv);
      hv[2] = __float2bfloat16(v.z * inv);
      hv[3] = __float2bfloat16(v.w * inv);
      *(ushort4*)&dst[(size_t)row * DDIM + l * 4] = *(ushort4*)hv;
    }
  }
  __threadfence();
  cg::this_grid().sync();

  // ---------------- phase 2: MFMA cos grid + fused stats ----------------
  {
    const int bx    = bid & (F_GRIDX - 1);     // 0..15
    const int chunk = bid >> 4;                // 0..15
    const int i0    = bx * F_ROWS_PER_BLOCK;
    const int rbase = i0 + w * 32;
    const int jb0   = chunk * JPER;

    // one 16B DMA per thread covers the 16 KB stage (64 rows x 256 B)
    const int srow = w * 4 + rl4;              // 0..63, distinct over (w,rl4)
    const int scol = p15 ^ (srow & 15);        // involution swizzle
    const int srcoff = srow * DDIM + scol * 8;
    char* const ldst0 = &lds0[w * 1024];       // wave-uniform base; lane*16 appended by HW
    char* const ldst1 = &lds1[w * 1024];

    // prologue: targets chunk (waves 0..7) + stage 0
    if (w < 8)
      __builtin_amdgcn_global_load_lds(
          (const AS1 void*)(targets + jb0 + w * 64 + lane),
          (AS3 void*)(&tsh[w * 64]), 4, 0, 0);
    __builtin_amdgcn_global_load_lds(
        (const AS1 void*)(f2b + (size_t)jb0 * DDIM + srcoff),
        (AS3 void*)ldst0, 16, 0, 0);

    // inline the stage loop with prefetch (same structure as R5)
    {
      // A fragments + ki + accumulators live in stats_wave_body; we need the DMA
      // interleaved with compute, so replicate R5's loop here around the body's math.
      // To keep the proven code path single-source, we do the staging here and call
      // the body's per-stage compute via the same loop shape:
      // (stats_wave_body performs __syncthreads between stages; we mirror its timing)
      // Issue pattern: sync -> prefetch s+1 -> compute s  (identical to R5)
      // First sync: stage-0 DMA complete.
      __syncthreads();
      #pragma unroll 1
      for (int s = 0; s < NSTAGES; ++s) {
        if (s + 1 < NSTAGES) {
          const __hip_bfloat16* gstage = f2b + (size_t)(jb0 + (s + 1) * STAGE_COLS) * DDIM;
          __builtin_amdgcn_global_load_lds(
              (const AS1 void*)(gstage + srcoff),
              (AS3 void*)(((s + 1) & 1) ? ldst1 : ldst0), 16, 0, 0);
        }
        if (s == 0) {
          // run the whole per-wave body once; it computes all stages itself and
          // issues __syncthreads between them, matching this loop's barriers.
          stats_wave_body(f1b, targets, partials, lds0, lds1, tsh, chunk, rbase, lane);
        }
        if (s + 1 < NSTAGES) {
          // body already did its per-stage __syncthreads for s>=1; we must match the
          // barrier count here only for s==0 path. For s>0 nothing to do.
        }
      }
    }
  }
  __threadfence();
  cg::this_grid().sync();

  // ---------------- phase 3: per-row loss + global mean (blocks 0..31, threads 0..255) ----------------
  if (bid < 32) {
    const int l3 = t & 63, wid = t >> 6;
    if (t < 256) {
      int r = bid * 256 + t;
      float Z = 0, Zp = 0, Cp = 0, Np = 0;
      for (int ch = 0; ch < JCHUNKS; ++ch) {
        float4 p = *(const float4*)&partials[((size_t)r * JCHUNKS + ch) * 4];
        Z += p.x; Zp += p.y; Cp += p.z; Np += p.w;
      }
      float Zn = Z - Zp;
      float nn = (float)NROWS - Np;
      float spos = (1.0f + logf(Z)) - Cp / Np;
      float sneg = Zn / Z - nn * 1e-10f;
      float per_row = spos + sneg / nn;

      float v = per_row;
      for (int off = 32; off; off >>= 1) v += __shfl_xor(v, off, 64);
      if (l3 == 0) wsum[wid] = v;
    }
    __syncthreads();
    if (t == 0)
      atomicAdd(out, (wsum[0] + wsum[1] + wsum[2] + wsum[3]) * (1.0f / (float)NROWS));
  }
}

// ======================= fallback: R5 three-kernel path (measured 98.7 us) =======================
__global__ __launch_bounds__(256) void norm_kernel(
    const float* __restrict__ f1, const float* __restrict__ f2,
    __hip_bfloat16* __restrict__ f1b, __hip_bfloat16* __restrict__ f2b,
    float* __restrict__ out) {
  if (blockIdx.x == 0 && threadIdx.x == 0) out[0] = 0.0f;
  int t = threadIdx.x;
  int rloc = t >> 5;
  int l = t & 31;
  int b = blockIdx.x;
  int half = (b >= NROWS / 8) ? 1 : 0;
  int row = (b - half * (NROWS / 8)) * 8 + rloc;
  const float* src = half ? f2 : f1;
  __hip_bfloat16* dst = half ? f2b : f1b;

  float4 v = ((const float4*)src)[row * (DDIM / 4) + l];
  float s = v.x * v.x + v.y * v.y + v.z * v.z + v.w * v.w;
  #pragma unroll
  for (int off = 1; off < 32; off <<= 1) s += __shfl_xor(s, off, 64);
  float inv = 1.0f / fmaxf(sqrtf(s), 1e-12f);
  __hip_bfloat16 hv[4];
  hv[0] = __float2bfloat16(v.x * inv);
  hv[1] = __float2bfloat16(v.y * inv);
  hv[2] = __float2bfloat16(v.z * inv);
  hv[3] = __float2bfloat16(v.w * inv);
  *(ushort4*)&dst[(size_t)row * DDIM + l * 4] = *(ushort4*)hv;
}

__global__ __launch_bounds__(512, 4) void stats_kernel(
    const __hip_bfloat16* __restrict__ f1b,
    const __hip_bfloat16* __restrict__ f2b,
    const float* __restrict__ targets,
    float* __restrict__ partials) {
  __shared__ __align__(16) char lds0[STAGE_COLS * 256];
  __shared__ __align__(16) char lds1[STAGE_COLS * 256];
  __shared__ __align__(16) float tsh[JPER];

  const int chunk = blockIdx.y;
  const int i0 = blockIdx.x * ROWS_PER_BLOCK;
  const int w    = threadIdx.x >> 6;
  const int lane = threadIdx.x & 63;
  const int p15  = lane & 15;
  const int rl4  = lane >> 4;
  const int rbase = i0 + w * 32;
  const int jb0 = chunk * JPER;

  int srcoff[2];
  #pragma unroll
  for (int q = 0; q < 2; ++q) {
    int rloc = w * 8 + q * 4 + rl4;
    int c    = p15 ^ (rloc & 15);
    srcoff[q] = rloc * DDIM + c * 8;
  }
  {
    __builtin_amdgcn_global_load_lds(
        (const AS1 void*)(targets + jb0 + w * 64 + lane),
        (AS3 void*)(&tsh[w * 64]), 4, 0, 0);
    const __hip_bfloat16* gstage = f2b + (size_t)jb0 * DDIM;
    char* lbase = &lds0[w * 2048];
    #pragma unroll
    for (int q = 0; q < 2; ++q)
      __builtin_amdgcn_global_load_lds((const AS1 void*)(gstage + srcoff[q]),
                                       (AS3 void*)(lbase + q * 1024), 16, 0, 0);
  }

  // same structure as R5 kernel: sync -> prefetch -> compute per stage, via shared body
  __syncthreads();
  #pragma unroll 1
  for (int s = 0; s < NSTAGES; ++s) {
    if (s + 1 < NSTAGES) {
      const __hip_bfloat16* gstage = f2b + (size_t)(jb0 + (s + 1) * STAGE_COLS) * DDIM;
      char* lbase = ((s + 1) & 1) ? &lds1[w * 2048] : &lds0[w * 2048];
      #pragma unroll
      for (int q = 0; q < 2; ++q)
        __builtin_amdgcn_global_load_lds((const AS1 void*)(gstage + srcoff[q]),
                                         (AS3 void*)(lbase + q * 1024), 16, 0, 0);
    }
    if (s == 0)
      stats_wave_body(f1b, targets, partials, lds0, lds1, tsh, chunk, rbase, lane);
  }
}

__global__ void finalize_rows(const float* __restrict__ partials,
                              float* __restrict__ out) {
  int r = blockIdx.x * 256 + threadIdx.x;
  float Z = 0, Zp = 0, Cp = 0, Np = 0;
  for (int ch = 0; ch < JCHUNKS; ++ch) {
    float4 p = *(const float4*)&partials[((size_t)r * JCHUNKS + ch) * 4];
    Z += p.x; Zp += p.y; Cp += p.z; Np += p.w;
  }
  float Zn = Z - Zp;
  float nn = (float)NROWS - Np;
  float spos = (1.0f + logf(Z)) - Cp / Np;
  float sneg = Zn / Z - nn * 1e-10f;
  float per_row = spos + sneg / nn;

  float v = per_row;
  for (int off = 32; off; off >>= 1) v += __shfl_xor(v, off, 64);
  __shared__ float wsum[4];
  int lane = threadIdx.x & 63, wid = threadIdx.x >> 6;
  if (lane == 0) wsum[wid] = v;
  __syncthreads();
  if (threadIdx.x == 0)
    atomicAdd(out, (wsum[0] + wsum[1] + wsum[2] + wsum[3]) * (1.0f / (float)NROWS));
}

// ---------------- launch ----------------
extern "C" void kernel_launch(void* const* d_in, const int* in_sizes, int n_in,
                              void* d_out, int out_size, void* d_ws, size_t ws_size,
                              hipStream_t stream) {
  const float* f1  = (const float*)d_in[0];
  const float* f2  = (const float*)d_in[1];
  const float* tgt = (const float*)d_in[2];
  float* out = (float*)d_out;

  char* ws = (char*)d_ws;
  __hip_bfloat16* f1b = (__hip_bfloat16*)ws;                       // 2 MB
  __hip_bfloat16* f2b = (__hip_bfloat16*)(ws + (size_t)NROWS * DDIM * 2);
  float* partials = (float*)(ws + (size_t)NROWS * DDIM * 4);       // 2 MB

  void* args[] = {(void*)&f1, (void*)&f2, (void*)&tgt, (void*)&out,
                  (void*)&f1b, (void*)&f2b, (void*)&partials};
  hipError_t rc = hipLaunchCooperativeKernel((const void*)fused_kernel,
                                             dim3(F_NBLK), dim3(1024),
                                             args, 0, stream);
  if (rc != hipSuccess) {
    (void)hipGetLastError();  // clear sticky error; fall back to proven 3-kernel path
    norm_kernel<<<2 * (NROWS / 8), 256, 0, stream>>>(f1, f2, f1b, f2b, out);
    dim3 g2(GRIDX, JCHUNKS);
    stats_kernel<<<g2, 512, 0, stream>>>(f1b, f2b, tgt, partials);
    finalize_rows<<<NROWS / 256, 256, 0, stream>>>(partials, out);
  }
}

// Round 9
// 116.659 us; speedup vs baseline: 3.0672x; 3.0672x over previous
//
#include <hip/hip_runtime.h>
#include <hip/hip_bf16.h>
#include <math.h>

#define NROWS 8192
#define DDIM  128
#define JCHUNKS 32
#define JPER  (NROWS / JCHUNKS)        // 256 cols per chunk
#define STAGE_COLS 64
#define NSTAGES (JPER / STAGE_COLS)    // 4
#define ROWS_PER_BLOCK 512             // 8 waves x 64 rows share one B-tile
#define GRIDX (NROWS / ROWS_PER_BLOCK) // 16  -> grid 16 x 32 = 512 blocks (2/CU)
#define LOG2E 1.44269504088896f

#define AS1 __attribute__((address_space(1)))
#define AS3 __attribute__((address_space(3)))

typedef __attribute__((ext_vector_type(8))) short bf16x8;  // 8 bf16 = 4 VGPRs
typedef __attribute__((ext_vector_type(4))) float f32x4;

// ---------------- kernel 1: L2 row-normalize -> bf16 (also zeroes out[0]) ----------------
__global__ __launch_bounds__(256) void norm_kernel(
    const float* __restrict__ f1, const float* __restrict__ f2,
    __hip_bfloat16* __restrict__ f1b, __hip_bfloat16* __restrict__ f2b,
    float* __restrict__ out) {
  if (blockIdx.x == 0 && threadIdx.x == 0) out[0] = 0.0f;  // stream-ordered before finalize
  int t = threadIdx.x;
  int rloc = t >> 5;                 // 0..7
  int l = t & 31;
  int b = blockIdx.x;                // 0..2047
  int half = (b >= NROWS / 8) ? 1 : 0;
  int row = (b - half * (NROWS / 8)) * 8 + rloc;
  const float* src = half ? f2 : f1;
  __hip_bfloat16* dst = half ? f2b : f1b;

  float4 v = ((const float4*)src)[row * (DDIM / 4) + l];
  float s = v.x * v.x + v.y * v.y + v.z * v.z + v.w * v.w;
  #pragma unroll
  for (int off = 1; off < 32; off <<= 1) s += __shfl_xor(s, off, 64);
  float inv = 1.0f / fmaxf(sqrtf(s), 1e-12f);
  __hip_bfloat16 hv[4];
  hv[0] = __float2bfloat16(v.x * inv);
  hv[1] = __float2bfloat16(v.y * inv);
  hv[2] = __float2bfloat16(v.z * inv);
  hv[3] = __float2bfloat16(v.w * inv);
  *(ushort4*)&dst[(size_t)row * DDIM + l * 4] = *(ushort4*)hv;
}

// ---------------- kernel 2: MFMA cos grid, 8 waves x 64 rows, 512 blocks ----------------
// R8 synthesis: R6's reuse test was confounded by halved wave count. This config holds
// occupancy at 4096 waves (4/SIMD, VGPR cap 128 via (512,2) == empirical waves_per_eu 4)
// while halving LDS rereads (64 rows/wave) and barrier count (4 stages of JPER=256).
// partials[(row*JCHUNKS + chunk)*4 + {Z,Zp,Cp,Np}]
__global__ __launch_bounds__(512, 2) void stats_kernel(
    const __hip_bfloat16* __restrict__ f1b,
    const __hip_bfloat16* __restrict__ f2b,
    const float* __restrict__ targets,
    float* __restrict__ partials) {
  __shared__ __align__(16) char lds0[STAGE_COLS * 256];   // 16 KB
  __shared__ __align__(16) char lds1[STAGE_COLS * 256];   // 16 KB
  __shared__ __align__(16) float tsh[JPER];               // 1 KB

  const int chunk = blockIdx.y;                  // 0..31
  const int i0 = blockIdx.x * ROWS_PER_BLOCK;
  const int w    = threadIdx.x >> 6;             // 0..7
  const int lane = threadIdx.x & 63;
  const int p15  = lane & 15;
  const int rl4  = lane >> 4;                    // quad
  const int rbase = i0 + w * 64;                 // this wave's 64 rows

  // ---- A fragments resident for whole sweep: A[m=p15][k = rl4*8 + ks*32 ..] ----
  bf16x8 afrag[4][4];
  #pragma unroll
  for (int rs = 0; rs < 4; ++rs) {
    const __hip_bfloat16* arow =
        &f1b[(size_t)(rbase + rs * 16 + p15) * DDIM + rl4 * 8];
    #pragma unroll
    for (int ks = 0; ks < 4; ++ks)
      afrag[rs][ks] = *(const bf16x8*)(arow + ks * 32);
  }

  // lane's C rows per rs: row = rbase + rs*16 + rl4*4 + rr  (reg rr of acc)
  f32x4 ki[4];
  #pragma unroll
  for (int rs = 0; rs < 4; ++rs)
    #pragma unroll
    for (int rr = 0; rr < 4; ++rr)
      ki[rs][rr] = targets[rbase + rs * 16 + rl4 * 4 + rr];

  f32x4 Z[4], Zp[4], Cp[4], Np[4];
  #pragma unroll
  for (int rs = 0; rs < 4; ++rs) {
    Z[rs] = (f32x4){0.f, 0.f, 0.f, 0.f};
    Zp[rs] = (f32x4){0.f, 0.f, 0.f, 0.f};
    Cp[rs] = (f32x4){0.f, 0.f, 0.f, 0.f};
    Np[rs] = (f32x4){0.f, 0.f, 0.f, 0.f};
  }

  const int jb0 = chunk * JPER;

  // ---- DMA source offsets within a 64-row stage block (2 rounds x 512 lanes x 16B = 16 KB)
  // LDS[row][x] = global[row][x ^ (row & 15)]  (involution swizzle; read undoes it)
  int srcoff[2];
  #pragma unroll
  for (int q = 0; q < 2; ++q) {
    int rloc = w * 8 + q * 4 + rl4;            // 0..63, distinct over (w,q,rl4)
    int c    = p15 ^ (rloc & 15);
    srcoff[q] = rloc * DDIM + c * 8;
  }

  // prologue: DMA targets chunk (256 floats, waves 0..3) + stage 0 -> lds0
  {
    if (w < 4)
      __builtin_amdgcn_global_load_lds(
          (const AS1 void*)(targets + jb0 + w * 64 + lane),
          (AS3 void*)(&tsh[w * 64]), 4, 0, 0);
    const __hip_bfloat16* gstage = f2b + (size_t)jb0 * DDIM;
    char* lbase = &lds0[w * 2048];
    #pragma unroll
    for (int q = 0; q < 2; ++q)
      __builtin_amdgcn_global_load_lds((const AS1 void*)(gstage + srcoff[q]),
                                       (AS3 void*)(lbase + q * 1024), 16, 0, 0);
  }

  for (int s = 0; s < NSTAGES; ++s) {
    __syncthreads();   // stage-s DMA complete; buf[(s+1)&1] free to overwrite

    if (s + 1 < NSTAGES) {
      const __hip_bfloat16* gstage = f2b + (size_t)(jb0 + (s + 1) * STAGE_COLS) * DDIM;
      char* lbase = ((s + 1) & 1) ? &lds1[w * 2048] : &lds0[w * 2048];
      #pragma unroll
      for (int q = 0; q < 2; ++q)
        __builtin_amdgcn_global_load_lds((const AS1 void*)(gstage + srcoff[q]),
                                         (AS3 void*)(lbase + q * 1024), 16, 0, 0);
    }

    const char* lb = (s & 1) ? lds1 : lds0;
    #pragma unroll
    for (int ct = 0; ct < 4; ++ct) {
      const int rloc = ct * 16 + p15;            // B row (col index n) in stage; rloc&15 == p15
      bf16x8 bfrag[4];
      #pragma unroll
      for (int ks = 0; ks < 4; ++ks)
        bfrag[ks] = *(const bf16x8*)(lb + rloc * 256 + (((rl4 + ks * 4) ^ p15) << 4));

      float tj = tsh[s * STAGE_COLS + ct * 16 + p15];  // quad-broadcast: conflict-free
      const bool pj = tj > 0.0f;
      const f32x4 tj4 = {tj, tj, tj, tj};
      const f32x4 K4  = {LOG2E, LOG2E, LOG2E, LOG2E};

      #pragma unroll
      for (int rs = 0; rs < 4; ++rs) {
        f32x4 acc = {0.f, 0.f, 0.f, 0.f};
        #pragma unroll
        for (int ks = 0; ks < 4; ++ks)
          acc = __builtin_amdgcn_mfma_f32_16x16x32_bf16(afrag[rs][ks], bfrag[ks], acc, 0, 0, 0);

        f32x4 c4 = acc;
        f32x4 d4 = ki[rs] - tj4;
        f32x4 m4;
        #pragma unroll
        for (int rr = 0; rr < 4; ++rr) {
          bool q = (__builtin_fabsf(d4[rr]) <= 0.1f) & ((ki[rs][rr] > 0.0f) == pj);
          m4[rr] = q ? 1.0f : 0.0f;
        }
        f32x4 x4 = c4 * K4 - K4;
        f32x4 e4;
        #pragma unroll
        for (int rr = 0; rr < 4; ++rr) e4[rr] = __builtin_amdgcn_exp2f(x4[rr]);
        Z[rs]  += e4;
        Zp[rs] += m4 * e4;
        Cp[rs] += m4 * c4;
        Np[rs] += m4;
      }
    }
  }

  // reduce over the 16 lanes (p15) sharing each row
  #pragma unroll
  for (int rs = 0; rs < 4; ++rs) {
    #pragma unroll
    for (int rr = 0; rr < 4; ++rr) {
      #pragma unroll
      for (int off = 1; off < 16; off <<= 1) {
        Z[rs][rr]  += __shfl_xor(Z[rs][rr],  off, 64);
        Zp[rs][rr] += __shfl_xor(Zp[rs][rr], off, 64);
        Cp[rs][rr] += __shfl_xor(Cp[rs][rr], off, 64);
        Np[rs][rr] += __shfl_xor(Np[rs][rr], off, 64);
      }
    }
  }
  if (p15 == 0) {
    #pragma unroll
    for (int rs = 0; rs < 4; ++rs)
      #pragma unroll
      for (int rr = 0; rr < 4; ++rr) {
        size_t row = rbase + rs * 16 + rl4 * 4 + rr;
        f32x4 st = {Z[rs][rr], Zp[rs][rr], Cp[rs][rr], Np[rs][rr]};
        *(f32x4*)&partials[((size_t)row * JCHUNKS + chunk) * 4] = st;
      }
  }
}

// ---------------- kernel 3: per-row loss + global mean (atomic) ----------------
__global__ void finalize_rows(const float* __restrict__ partials,
                              float* __restrict__ out) {
  int r = blockIdx.x * 256 + threadIdx.x;   // grid 32 x 256
  float Z = 0, Zp = 0, Cp = 0, Np = 0;
  for (int ch = 0; ch < JCHUNKS; ++ch) {
    float4 p = *(const float4*)&partials[((size_t)r * JCHUNKS + ch) * 4];
    Z += p.x; Zp += p.y; Cp += p.z; Np += p.w;
  }
  float Zn = Z - Zp;
  float nn = (float)NROWS - Np;
  float spos = (1.0f + logf(Z)) - Cp / Np;
  float sneg = Zn / Z - nn * 1e-10f;
  float per_row = spos + sneg / nn;

  float v = per_row;
  for (int off = 32; off; off >>= 1) v += __shfl_xor(v, off, 64);
  __shared__ float wsum[4];
  int lane = threadIdx.x & 63, wid = threadIdx.x >> 6;
  if (lane == 0) wsum[wid] = v;
  __syncthreads();
  if (threadIdx.x == 0)
    atomicAdd(out, (wsum[0] + wsum[1] + wsum[2] + wsum[3]) * (1.0f / (float)NROWS));
}

// ---------------- launch ----------------
extern "C" void kernel_launch(void* const* d_in, const int* in_sizes, int n_in,
                              void* d_out, int out_size, void* d_ws, size_t ws_size,
                              hipStream_t stream) {
  const float* f1  = (const float*)d_in[0];
  const float* f2  = (const float*)d_in[1];
  const float* tgt = (const float*)d_in[2];
  float* out = (float*)d_out;

  char* ws = (char*)d_ws;
  __hip_bfloat16* f1b = (__hip_bfloat16*)ws;                       // 2 MB
  __hip_bfloat16* f2b = (__hip_bfloat16*)(ws + (size_t)NROWS * DDIM * 2);
  float* partials = (float*)(ws + (size_t)NROWS * DDIM * 4);       // 4 MB

  norm_kernel<<<2 * (NROWS / 8), 256, 0, stream>>>(f1, f2, f1b, f2b, out);
  dim3 g2(GRIDX, JCHUNKS);
  stats_kernel<<<g2, 512, 0, stream>>>(f1b, f2b, tgt, partials);
  finalize_rows<<<NROWS / 256, 256, 0, stream>>>(partials, out);
}

// Round 10
// 105.065 us; speedup vs baseline: 3.4056x; 1.1104x over previous
//
#include <hip/hip_runtime.h>
#include <hip/hip_bf16.h>
#include <math.h>

#define NROWS 8192
#define DDIM  128
#define JCHUNKS 16
#define JPER  (NROWS / JCHUNKS)        // 512 cols per chunk
#define STAGE_COLS 128
#define NSTAGES (JPER / STAGE_COLS)    // 4
#define ROWS_PER_BLOCK 256             // 8 waves x 32 rows share one B-tile
#define GRIDX (NROWS / ROWS_PER_BLOCK) // 32 -> grid 32 x 16 = 512 blocks (2/CU)
#define LOG2E 1.44269504088896f

#define AS1 __attribute__((address_space(1)))
#define AS3 __attribute__((address_space(3)))

typedef __attribute__((ext_vector_type(8))) short bf16x8;  // 8 bf16 = 4 VGPRs
typedef __attribute__((ext_vector_type(4))) float f32x4;
typedef __attribute__((ext_vector_type(2))) float f32x2;

// ---------------- kernel 1: L2 row-normalize -> bf16 (also zeroes out[0]) ----------------
__global__ __launch_bounds__(256) void norm_kernel(
    const float* __restrict__ f1, const float* __restrict__ f2,
    __hip_bfloat16* __restrict__ f1b, __hip_bfloat16* __restrict__ f2b,
    float* __restrict__ out) {
  if (blockIdx.x == 0 && threadIdx.x == 0) out[0] = 0.0f;  // stream-ordered before finalize
  int t = threadIdx.x;
  int rloc = t >> 5;                 // 0..7
  int l = t & 31;
  int b = blockIdx.x;                // 0..2047
  int half = (b >= NROWS / 8) ? 1 : 0;
  int row = (b - half * (NROWS / 8)) * 8 + rloc;
  const float* src = half ? f2 : f1;
  __hip_bfloat16* dst = half ? f2b : f1b;

  float4 v = ((const float4*)src)[row * (DDIM / 4) + l];
  float s = v.x * v.x + v.y * v.y + v.z * v.z + v.w * v.w;
  #pragma unroll
  for (int off = 1; off < 32; off <<= 1) s += __shfl_xor(s, off, 64);
  float inv = 1.0f / fmaxf(sqrtf(s), 1e-12f);
  __hip_bfloat16 hv[4];
  hv[0] = __float2bfloat16(v.x * inv);
  hv[1] = __float2bfloat16(v.y * inv);
  hv[2] = __float2bfloat16(v.z * inv);
  hv[3] = __float2bfloat16(v.w * inv);
  *(ushort4*)&dst[(size_t)row * DDIM + l * 4] = *(ushort4*)hv;
}

// ---------------- kernel 2: MFMA cos grid — R5 structure (best measured, ~37.5us) ----------------
// + STAGE_COLS=128: halves barrier/drain events (8->4); same global j-order -> bit-exact.
// + epilogue in aligned f32x2 pairs (acc[0:1], acc[2:3]) for v_pk_*_f32 emission.
// rs=2 per session-wide evidence: every rs=4 variant (R2/R6/R9, VGPR 108) lost to rs=2 (64-68).
// partials[(row*JCHUNKS + chunk)*4 + {Z,Zp,Cp,Np}]
__global__ __launch_bounds__(512, 3) void stats_kernel(
    const __hip_bfloat16* __restrict__ f1b,
    const __hip_bfloat16* __restrict__ f2b,
    const float* __restrict__ targets,
    float* __restrict__ partials) {
  __shared__ __align__(16) char lds0[STAGE_COLS * 256];   // 32 KB
  __shared__ __align__(16) char lds1[STAGE_COLS * 256];   // 32 KB
  __shared__ __align__(16) float tsh[JPER];               // 2 KB

  const int chunk = blockIdx.y;                  // 0..15
  const int i0 = blockIdx.x * ROWS_PER_BLOCK;
  const int w    = threadIdx.x >> 6;             // 0..7
  const int lane = threadIdx.x & 63;
  const int p15  = lane & 15;
  const int rl4  = lane >> 4;                    // quad
  const int rbase = i0 + w * 32;                 // this wave's 32 rows

  // ---- A fragments resident for whole sweep: A[m=p15][k = rl4*8 + ks*32 ..] ----
  bf16x8 afrag[2][4];
  #pragma unroll
  for (int rs = 0; rs < 2; ++rs) {
    const __hip_bfloat16* arow =
        &f1b[(size_t)(rbase + rs * 16 + p15) * DDIM + rl4 * 8];
    #pragma unroll
    for (int ks = 0; ks < 4; ++ks)
      afrag[rs][ks] = *(const bf16x8*)(arow + ks * 32);
  }

  // lane's C rows per rs: row = rbase + rs*16 + rl4*4 + (2h+c)
  f32x2 ki2[2][2];
  #pragma unroll
  for (int rs = 0; rs < 2; ++rs)
    #pragma unroll
    for (int h = 0; h < 2; ++h) {
      ki2[rs][h][0] = targets[rbase + rs * 16 + rl4 * 4 + 2 * h + 0];
      ki2[rs][h][1] = targets[rbase + rs * 16 + rl4 * 4 + 2 * h + 1];
    }

  f32x2 Z2[2][2], Zp2[2][2], Cp2[2][2], Np2[2][2];
  #pragma unroll
  for (int rs = 0; rs < 2; ++rs)
    #pragma unroll
    for (int h = 0; h < 2; ++h) {
      Z2[rs][h] = (f32x2){0.f, 0.f};
      Zp2[rs][h] = (f32x2){0.f, 0.f};
      Cp2[rs][h] = (f32x2){0.f, 0.f};
      Np2[rs][h] = (f32x2){0.f, 0.f};
    }

  const int jb0 = chunk * JPER;

  // ---- DMA source offsets within a 128-row stage block (4 rounds x 512 lanes x 16B = 32 KB)
  // LDS[row][x] = global[row][x ^ (row & 15)]  (involution swizzle; read undoes it)
  int srcoff[4];
  #pragma unroll
  for (int q = 0; q < 4; ++q) {
    int rloc = w * 16 + q * 4 + rl4;           // 0..127, distinct over (w,q,rl4)
    int c    = p15 ^ (rloc & 15);
    srcoff[q] = rloc * DDIM + c * 8;
  }

  // prologue: DMA targets chunk (512 floats, 1 round) + stage 0 -> lds0
  {
    __builtin_amdgcn_global_load_lds(
        (const AS1 void*)(targets + jb0 + w * 64 + lane),
        (AS3 void*)(&tsh[w * 64]), 4, 0, 0);
    const __hip_bfloat16* gstage = f2b + (size_t)jb0 * DDIM;
    char* lbase = &lds0[w * 4096];
    #pragma unroll
    for (int q = 0; q < 4; ++q)
      __builtin_amdgcn_global_load_lds((const AS1 void*)(gstage + srcoff[q]),
                                       (AS3 void*)(lbase + q * 1024), 16, 0, 0);
  }

  for (int s = 0; s < NSTAGES; ++s) {
    __syncthreads();   // stage-s DMA complete; buf[(s+1)&1] free to overwrite

    if (s + 1 < NSTAGES) {
      const __hip_bfloat16* gstage = f2b + (size_t)(jb0 + (s + 1) * STAGE_COLS) * DDIM;
      char* lbase = ((s + 1) & 1) ? &lds1[w * 4096] : &lds0[w * 4096];
      #pragma unroll
      for (int q = 0; q < 4; ++q)
        __builtin_amdgcn_global_load_lds((const AS1 void*)(gstage + srcoff[q]),
                                         (AS3 void*)(lbase + q * 1024), 16, 0, 0);
    }

    const char* lb = (s & 1) ? lds1 : lds0;
    #pragma unroll
    for (int ct = 0; ct < 8; ++ct) {
      const int rloc = ct * 16 + p15;            // B row in stage (0..127); rloc&15 == p15
      bf16x8 bfrag[4];
      #pragma unroll
      for (int ks = 0; ks < 4; ++ks)
        bfrag[ks] = *(const bf16x8*)(lb + rloc * 256 + (((rl4 + ks * 4) ^ p15) << 4));

      float tj = tsh[s * STAGE_COLS + ct * 16 + p15];  // quad-broadcast: conflict-free
      const bool pj = tj > 0.0f;
      const f32x2 tj2 = {tj, tj};
      const f32x2 K2  = {LOG2E, LOG2E};

      #pragma unroll
      for (int rs = 0; rs < 2; ++rs) {
        f32x4 acc = {0.f, 0.f, 0.f, 0.f};
        #pragma unroll
        for (int ks = 0; ks < 4; ++ks)
          acc = __builtin_amdgcn_mfma_f32_16x16x32_bf16(afrag[rs][ks], bfrag[ks], acc, 0, 0, 0);

        // epilogue on aligned register pairs (acc[0:1], acc[2:3]) -> v_pk friendly
        #pragma unroll
        for (int h = 0; h < 2; ++h) {
          f32x2 c2 = {acc[2 * h + 0], acc[2 * h + 1]};
          f32x2 d2 = ki2[rs][h] - tj2;
          bool q0 = (__builtin_fabsf(d2[0]) <= 0.1f) & ((ki2[rs][h][0] > 0.0f) == pj);
          bool q1 = (__builtin_fabsf(d2[1]) <= 0.1f) & ((ki2[rs][h][1] > 0.0f) == pj);
          f32x2 m2 = {q0 ? 1.0f : 0.0f, q1 ? 1.0f : 0.0f};
          f32x2 x2 = c2 * K2 - K2;
          f32x2 e2 = {__builtin_amdgcn_exp2f(x2[0]), __builtin_amdgcn_exp2f(x2[1])};
          Z2[rs][h]  += e2;
          Zp2[rs][h] += m2 * e2;
          Cp2[rs][h] += m2 * c2;
          Np2[rs][h] += m2;
        }
      }
    }
  }

  // reduce over the 16 lanes (p15) sharing each row
  #pragma unroll
  for (int rs = 0; rs < 2; ++rs)
    #pragma unroll
    for (int h = 0; h < 2; ++h)
      #pragma unroll
      for (int c = 0; c < 2; ++c)
        #pragma unroll
        for (int off = 1; off < 16; off <<= 1) {
          Z2[rs][h][c]  += __shfl_xor(Z2[rs][h][c],  off, 64);
          Zp2[rs][h][c] += __shfl_xor(Zp2[rs][h][c], off, 64);
          Cp2[rs][h][c] += __shfl_xor(Cp2[rs][h][c], off, 64);
          Np2[rs][h][c] += __shfl_xor(Np2[rs][h][c], off, 64);
        }
  if (p15 == 0) {
    #pragma unroll
    for (int rs = 0; rs < 2; ++rs)
      #pragma unroll
      for (int h = 0; h < 2; ++h)
        #pragma unroll
        for (int c = 0; c < 2; ++c) {
          size_t row = rbase + rs * 16 + rl4 * 4 + 2 * h + c;
          f32x4 st = {Z2[rs][h][c], Zp2[rs][h][c], Cp2[rs][h][c], Np2[rs][h][c]};
          *(f32x4*)&partials[((size_t)row * JCHUNKS + chunk) * 4] = st;
        }
  }
}

// ---------------- kernel 3: per-row loss + global mean (atomic) ----------------
__global__ void finalize_rows(const float* __restrict__ partials,
                              float* __restrict__ out) {
  int r = blockIdx.x * 256 + threadIdx.x;   // grid 32 x 256
  float Z = 0, Zp = 0, Cp = 0, Np = 0;
  for (int ch = 0; ch < JCHUNKS; ++ch) {
    float4 p = *(const float4*)&partials[((size_t)r * JCHUNKS + ch) * 4];
    Z += p.x; Zp += p.y; Cp += p.z; Np += p.w;
  }
  float Zn = Z - Zp;
  float nn = (float)NROWS - Np;
  float spos = (1.0f + logf(Z)) - Cp / Np;
  float sneg = Zn / Z - nn * 1e-10f;
  float per_row = spos + sneg / nn;

  float v = per_row;
  for (int off = 32; off; off >>= 1) v += __shfl_xor(v, off, 64);
  __shared__ float wsum[4];
  int lane = threadIdx.x & 63, wid = threadIdx.x >> 6;
  if (lane == 0) wsum[wid] = v;
  __syncthreads();
  if (threadIdx.x == 0)
    atomicAdd(out, (wsum[0] + wsum[1] + wsum[2] + wsum[3]) * (1.0f / (float)NROWS));
}

// ---------------- launch ----------------
extern "C" void kernel_launch(void* const* d_in, const int* in_sizes, int n_in,
                              void* d_out, int out_size, void* d_ws, size_t ws_size,
                              hipStream_t stream) {
  const float* f1  = (const float*)d_in[0];
  const float* f2  = (const float*)d_in[1];
  const float* tgt = (const float*)d_in[2];
  float* out = (float*)d_out;

  char* ws = (char*)d_ws;
  __hip_bfloat16* f1b = (__hip_bfloat16*)ws;                       // 2 MB
  __hip_bfloat16* f2b = (__hip_bfloat16*)(ws + (size_t)NROWS * DDIM * 2);
  float* partials = (float*)(ws + (size_t)NROWS * DDIM * 4);       // 2 MB

  norm_kernel<<<2 * (NROWS / 8), 256, 0, stream>>>(f1, f2, f1b, f2b, out);
  dim3 g2(GRIDX, JCHUNKS);
  stats_kernel<<<g2, 512, 0, stream>>>(f1b, f2b, tgt, partials);
  finalize_rows<<<NROWS / 256, 256, 0, stream>>>(partials, out);
}